// Round 1
// baseline (2016.840 us; speedup 1.0000x reference)
//
#include <hip/hip_runtime.h>
#include <hip/hip_bf16.h>
#include <stdint.h>

#define DEV __device__ __forceinline__

// ---------------- Threefry-2x32 (exact JAX semantics) ----------------
// key schedule: ks2 = k0^k1^0x1BD11BDA; rotations R0={13,15,26,6}, R1={17,29,16,24}
// groups R0,R1,R0,R1,R0 with subkey injection + round-counter after each group.

DEV uint32_t rotl32(uint32_t x, uint32_t r) { return (x << r) | (x >> (32u - r)); }

// partitionable 32-bit draw for flat index n: counter=(0,n), return o0^o1
DEV uint32_t tf_bits(uint32_t k0, uint32_t k1, uint32_t n) {
  uint32_t ks2 = k0 ^ k1 ^ 0x1BD11BDAu;
  uint32_t x0 = k0;        // c0 = 0 (+k0)
  uint32_t x1 = n + k1;    // c1 = n (+k1)
#define TF_R(r) { x0 += x1; x1 = rotl32(x1, r) ^ x0; }
  TF_R(13) TF_R(15) TF_R(26) TF_R(6)   x0 += k1;  x1 += ks2 + 1u;
  TF_R(17) TF_R(29) TF_R(16) TF_R(24)  x0 += ks2; x1 += k0 + 2u;
  TF_R(13) TF_R(15) TF_R(26) TF_R(6)   x0 += k0;  x1 += k1 + 3u;
  TF_R(17) TF_R(29) TF_R(16) TF_R(24)  x0 += k1;  x1 += ks2 + 4u;
  TF_R(13) TF_R(15) TF_R(26) TF_R(6)   x0 += ks2; x1 += k0 + 5u;
#undef TF_R
  return x0 ^ x1;
}

// constexpr host-side threefry for fold_in key derivation (compile-time)
struct KP { uint32_t a, b; };
constexpr KP tf_pair_ct(uint32_t k0, uint32_t k1, uint32_t c0, uint32_t c1) {
  uint32_t ks2 = k0 ^ k1 ^ 0x1BD11BDAu;
  uint32_t x0 = c0 + k0, x1 = c1 + k1;
  const uint32_t R[2][4] = {{13u,15u,26u,6u},{17u,29u,16u,24u}};
  uint32_t ks[3] = {k0, k1, ks2};
  for (int g = 0; g < 5; ++g) {
    for (int j = 0; j < 4; ++j) {
      x0 += x1;
      uint32_t r = R[g & 1][j];
      x1 = ((x1 << r) | (x1 >> (32u - r))) ^ x0;
    }
    x0 += ks[(g + 1) % 3];
    x1 += ks[(g + 2) % 3] + (uint32_t)(g + 1);
  }
  return {x0, x1};
}

template <int H> struct KeyArr { uint32_t k0[H]; uint32_t k1[H]; };
template <int H> constexpr KeyArr<H> make_keys(uint32_t seed) {
  KeyArr<H> K{};
  for (int i = 0; i < H; ++i) {
    // fold_in(key(seed), i) = threefry((0,seed), (0,i))
    KP p = tf_pair_ct(0u, seed, 0u, (uint32_t)i);
    K.k0[i] = p.a; K.k1[i] = p.b;
  }
  return K;
}

// _BASE = 0 ; seeds: x_exp=0(h=10), x_frac=1(h=6), w_exp=2(h=12), w_frac=3(h=8)
constexpr KeyArr<10> XE = make_keys<10>(0u);
constexpr KeyArr<6>  XF = make_keys<6>(1u);
constexpr KeyArr<12> WE = make_keys<12>(2u);
constexpr KeyArr<8>  WF = make_keys<8>(3u);

#define EXP_MASK  0x7F800000u
#define FRAC_MASK 0x007FFFFFu

template <int HE, int HF>
DEV float bitflip_val(float v, const KeyArr<HE>& KE, const KeyArr<HF>& KF,
                      uint32_t n, float zero_t) {
  uint32_t bits = __float_as_uint(v);
  uint32_t me = EXP_MASK;
#pragma unroll
  for (int h = 0; h < HE; ++h) me &= tf_bits(KE.k0[h], KE.k1[h], n);
  uint32_t mf = FRAC_MASK;
#pragma unroll
  for (int h = 0; h < HF; ++h) mf &= tf_bits(KF.k0[h], KF.k1[h], n);
  bits ^= (me | mf);
  float y = __uint_as_float(bits);
  bool finite = (bits & EXP_MASK) != EXP_MASK;
  float ay = __uint_as_float(bits & 0x7FFFFFFFu);
  return (finite && (ay <= zero_t)) ? y : 0.0f;
}

DEV uint16_t f32_to_bf16_rne(float f) {
  uint32_t u = __float_as_uint(f);
  u += 0x7FFFu + ((u >> 16) & 1u);
  return (uint16_t)(u >> 16);
}

// ---------------- Stage 1: bitflip(x) -> bf16 ----------------
__global__ void k_bitflip_x(const float* __restrict__ x, uint16_t* __restrict__ xb, int n_total) {
  int stride = gridDim.x * blockDim.x;
  for (int i = blockIdx.x * blockDim.x + threadIdx.x; i < n_total; i += stride) {
    float y = bitflip_val<10, 6>(x[i], XE, XF, (uint32_t)i, 1000.0f);
    xb[i] = f32_to_bf16_rne(y);
  }
}

// ---------------- Stage 2: w = weight + loraB@loraA (scaling=1), bitflip -> bf16 ----------------
__global__ void k_make_wb(const float* __restrict__ weight, const float* __restrict__ lA,
                          const float* __restrict__ lB, uint16_t* __restrict__ wb, int n_total) {
  int stride = gridDim.x * blockDim.x;
  for (int i = blockIdx.x * blockDim.x + threadIdx.x; i < n_total; i += stride) {
    int o = i >> 12;          // D_IN = 4096
    int c = i & 4095;
    float acc = weight[i];
#pragma unroll
    for (int r = 0; r < 32; ++r)
      acc += lB[(o << 5) + r] * lA[(r << 12) + c];
    float y = bitflip_val<12, 8>(acc, WE, WF, (uint32_t)i, 100.0f);
    wb[i] = f32_to_bf16_rne(y);
  }
}

// ---------------- Stage 3: GEMM  C[m,n] = sum_k A[m,k]*B[n,k]  (bf16 MFMA, m97 structure) ----------------
typedef __bf16 bf16x8_t __attribute__((ext_vector_type(8)));
typedef float  f32x4_t  __attribute__((ext_vector_type(4)));

DEV void gload_lds16(const uint16_t* g, uint16_t* l) {
  __builtin_amdgcn_global_load_lds((const __attribute__((address_space(1))) void*)g,
                                   (__attribute__((address_space(3))) void*)l, 16, 0, 0);
}

__global__ __launch_bounds__(256)
void k_gemm(const uint16_t* __restrict__ A, const uint16_t* __restrict__ B,
            float* __restrict__ C, int M, int N, int K) {
  __shared__ __align__(16) uint16_t As[128 * 32];
  __shared__ __align__(16) uint16_t Bs[128 * 32];

  // XCD-aware bijective swizzle (gridDim divisible by 8)
  int bid = blockIdx.x;
  int cpx = gridDim.x >> 3;
  int wg  = (bid & 7) * cpx + (bid >> 3);
  int ntiles = N >> 7;
  int tm = (wg / ntiles) << 7;
  int tn = (wg % ntiles) << 7;

  int tid  = threadIdx.x;
  int lane = tid & 63;
  int wid  = tid >> 6;           // 4 waves, 2x2 -> each owns 64x64
  int wm = (wid >> 1) << 6;
  int wn = (wid & 1) << 6;

  f32x4_t acc[4][4] = {};

  int fr = lane & 15;            // fragment row (A) / row (B)
  int kg = (lane >> 4) << 3;     // k-offset within BK=32

  // staging: each wave stages 32 rows of A and 32 rows of B (2x 16-row chunks)
  int srow = lane >> 2;          // 0..15
  int scol = (lane & 3) << 3;    // bf16 col offset: 4 x 16B per row
  const uint16_t* gA = A + (size_t)(tm + (wid << 5) + srow) * K + scol;
  const uint16_t* gB = B + (size_t)(tn + (wid << 5) + srow) * K + scol;
  uint16_t* lA0 = &As[((wid << 5) + 0) * 32];
  uint16_t* lA1 = &As[((wid << 5) + 16) * 32];
  uint16_t* lB0 = &Bs[((wid << 5) + 0) * 32];
  uint16_t* lB1 = &Bs[((wid << 5) + 16) * 32];

  for (int k0 = 0; k0 < K; k0 += 32) {
    gload_lds16(gA, lA0);
    gload_lds16(gA + 16 * (size_t)K, lA1);
    gload_lds16(gB, lB0);
    gload_lds16(gB + 16 * (size_t)K, lB1);
    __syncthreads();   // drains vmcnt before barrier

    bf16x8_t af[4], bfr[4];
#pragma unroll
    for (int m = 0; m < 4; ++m)
      af[m] = *(const bf16x8_t*)&As[(wm + (m << 4) + fr) * 32 + kg];
#pragma unroll
    for (int n = 0; n < 4; ++n)
      bfr[n] = *(const bf16x8_t*)&Bs[(wn + (n << 4) + fr) * 32 + kg];

#pragma unroll
    for (int m = 0; m < 4; ++m)
#pragma unroll
      for (int n = 0; n < 4; ++n)
        acc[m][n] = __builtin_amdgcn_mfma_f32_16x16x32_bf16(af[m], bfr[n], acc[m][n], 0, 0, 0);

    __syncthreads();
    gA += 32; gB += 32;
  }

  // C/D layout (verified m89): col = lane&15, row = (lane>>4)*4 + reg
  int crow = tm + wm + ((lane >> 4) << 2);
  int ccol = tn + wn + (lane & 15);
#pragma unroll
  for (int m = 0; m < 4; ++m)
#pragma unroll
    for (int n = 0; n < 4; ++n)
#pragma unroll
      for (int j = 0; j < 4; ++j)
        C[(size_t)(crow + (m << 4) + j) * N + (ccol + (n << 4))] = acc[m][n][j];
}

// ---------------- launch ----------------
extern "C" void kernel_launch(void* const* d_in, const int* in_sizes, int n_in,
                              void* d_out, int out_size, void* d_ws, size_t ws_size,
                              hipStream_t stream) {
  const float* x      = (const float*)d_in[0];
  const float* weight = (const float*)d_in[1];
  const float* lA     = (const float*)d_in[2];
  const float* lB     = (const float*)d_in[3];
  float* out = (float*)d_out;

  const int M = 4 * 2048;   // B*S
  const int N = 4096;       // D_OUT
  const int K = 4096;       // D_IN

  size_t need = (size_t)M * K * 2 + (size_t)N * K * 2;
  if (ws_size < need) return;  // workspace too small -> clean failure

  uint16_t* xb = (uint16_t*)d_ws;
  uint16_t* wb = xb + (size_t)M * K;

  k_bitflip_x<<<4096, 256, 0, stream>>>(x, xb, M * K);
  k_make_wb<<<4096, 256, 0, stream>>>(weight, lA, lB, wb, N * K);

  dim3 grid((M / 128) * (N / 128));   // 2048, divisible by 8
  k_gemm<<<grid, 256, 0, stream>>>(xb, wb, out, M, N, K);
}

// Round 2
// 1855.361 us; speedup vs baseline: 1.0870x; 1.0870x over previous
//
#include <hip/hip_runtime.h>
#include <hip/hip_bf16.h>
#include <stdint.h>

#define DEV __device__ __forceinline__

// ---------------- Threefry-2x32 (exact JAX semantics, partitionable path) ----
// counter=(0,n), draw = out0^out1. Rotation via v_alignbit_b32 (1 instr).

DEV uint32_t rotl32(uint32_t x, uint32_t r) {
  // rotl(x,r) == rotr(x,32-r) == alignbit(x,x,32-r)
  return __builtin_amdgcn_alignbit(x, x, 32u - r);
}

DEV uint32_t tf_bits(uint32_t k0, uint32_t k1, uint32_t n) {
  uint32_t ks2 = k0 ^ k1 ^ 0x1BD11BDAu;
  uint32_t x1 = n + k1;
  uint32_t x0 = k0 + x1;                 // round-1 "x0 += x1" folded into init
  x1 = rotl32(x1, 13) ^ x0;
#define TF_R(r) { x0 += x1; x1 = rotl32(x1, r) ^ x0; }
  TF_R(15) TF_R(26) TF_R(6)             x0 += k1;  x1 += ks2 + 1u;
  TF_R(17) TF_R(29) TF_R(16) TF_R(24)   x0 += ks2; x1 += k0 + 2u;
  TF_R(13) TF_R(15) TF_R(26) TF_R(6)    x0 += k0;  x1 += k1 + 3u;
  TF_R(17) TF_R(29) TF_R(16) TF_R(24)   x0 += k1;  x1 += ks2 + 4u;
  TF_R(13) TF_R(15) TF_R(26) TF_R(6)    x0 += ks2; x1 += k0 + 5u;
#undef TF_R
  return x0 ^ x1;
}

// constexpr host-side threefry for fold_in key derivation (compile-time)
struct KP { uint32_t a, b; };
constexpr KP tf_pair_ct(uint32_t k0, uint32_t k1, uint32_t c0, uint32_t c1) {
  uint32_t ks2 = k0 ^ k1 ^ 0x1BD11BDAu;
  uint32_t x0 = c0 + k0, x1 = c1 + k1;
  const uint32_t R[2][4] = {{13u,15u,26u,6u},{17u,29u,16u,24u}};
  uint32_t ks[3] = {k0, k1, ks2};
  for (int g = 0; g < 5; ++g) {
    for (int j = 0; j < 4; ++j) {
      x0 += x1;
      uint32_t r = R[g & 1][j];
      x1 = ((x1 << r) | (x1 >> (32u - r))) ^ x0;
    }
    x0 += ks[(g + 1) % 3];
    x1 += ks[(g + 2) % 3] + (uint32_t)(g + 1);
  }
  return {x0, x1};
}

template <int H> struct KeyArr { uint32_t k0[H]; uint32_t k1[H]; };
template <int H> constexpr KeyArr<H> make_keys(uint32_t seed) {
  KeyArr<H> K{};
  for (int i = 0; i < H; ++i) {
    KP p = tf_pair_ct(0u, seed, 0u, (uint32_t)i);
    K.k0[i] = p.a; K.k1[i] = p.b;
  }
  return K;
}

constexpr KeyArr<10> XE = make_keys<10>(0u);
constexpr KeyArr<6>  XF = make_keys<6>(1u);
constexpr KeyArr<12> WE = make_keys<12>(2u);
constexpr KeyArr<8>  WF = make_keys<8>(3u);

#define EXP_MASK  0x7F800000u
#define FRAC_MASK 0x007FFFFFu

template <int HE, int HF>
DEV uint32_t flip_bits(float v, const KeyArr<HE>& KE, const KeyArr<HF>& KF,
                       uint32_t n, float zero_t) {
  uint32_t bits = __float_as_uint(v);
  uint32_t me = EXP_MASK;
#pragma unroll
  for (int h = 0; h < HE; ++h) me &= tf_bits(KE.k0[h], KE.k1[h], n);
  uint32_t mf = FRAC_MASK;
#pragma unroll
  for (int h = 0; h < HF; ++h) mf &= tf_bits(KF.k0[h], KF.k1[h], n);
  bits ^= (me | mf);
  bool finite = (bits & EXP_MASK) != EXP_MASK;
  float ay = __uint_as_float(bits & 0x7FFFFFFFu);
  return (finite && (ay <= zero_t)) ? bits : 0u;
}

// round both fp32 (as raw bits) to bf16-RNE, pack into one u32 (lo=first)
DEV uint32_t pack2_bf16(uint32_t u0, uint32_t u1) {
  u0 += 0x7FFFu + ((u0 >> 16) & 1u);
  u1 += 0x7FFFu + ((u1 >> 16) & 1u);
  // dst bytes [3,2,1,0] = [u1.b3, u1.b2, u0.b3, u0.b2]; u1 is src0 (bytes 4-7)
  return __builtin_amdgcn_perm(u1, u0, 0x07060302u);
}

// ---------------- Stage 1: bitflip(x) -> bf16 (2 elems/thread/iter) ---------
__global__ __launch_bounds__(256)
void k_bitflip_x(const float2* __restrict__ x, uint32_t* __restrict__ xb, int n_pairs) {
  int stride = gridDim.x * blockDim.x;
#pragma unroll 1
  for (int p = blockIdx.x * blockDim.x + threadIdx.x; p < n_pairs; p += stride) {
    float2 v = x[p];
    uint32_t n0 = (uint32_t)p * 2u;
    uint32_t b0 = flip_bits<10, 6>(v.x, XE, XF, n0,      1000.0f);
    uint32_t b1 = flip_bits<10, 6>(v.y, XE, XF, n0 + 1u, 1000.0f);
    xb[p] = pack2_bf16(b0, b1);
  }
}

// ---------------- Stage 2: w = weight + loraB@loraA, bitflip -> bf16 --------
__global__ __launch_bounds__(256)
void k_make_wb(const float2* __restrict__ weight, const float* __restrict__ lA,
               const float* __restrict__ lB, uint32_t* __restrict__ wb, int n_pairs) {
  int stride = gridDim.x * blockDim.x;
#pragma unroll 1
  for (int p = blockIdx.x * blockDim.x + threadIdx.x; p < n_pairs; p += stride) {
    uint32_t n0 = (uint32_t)p * 2u;
    int o = (int)(n0 >> 12);          // D_IN = 4096
    int c = (int)(n0 & 4095u);
    float2 acc = weight[p];
#pragma unroll
    for (int r = 0; r < 32; ++r) {
      float2 a = *(const float2*)&lA[(r << 12) + c];
      float  b = lB[(o << 5) + r];
      acc.x += b * a.x;
      acc.y += b * a.y;
    }
    uint32_t b0 = flip_bits<12, 8>(acc.x, WE, WF, n0,      100.0f);
    uint32_t b1 = flip_bits<12, 8>(acc.y, WE, WF, n0 + 1u, 100.0f);
    wb[p] = pack2_bf16(b0, b1);
  }
}

// ---------------- Stage 3: GEMM  C[m,n] = sum_k A[m,k]*B[n,k]  (m97 structure)
typedef __bf16 bf16x8_t __attribute__((ext_vector_type(8)));
typedef float  f32x4_t  __attribute__((ext_vector_type(4)));

DEV void gload_lds16(const uint16_t* g, uint16_t* l) {
  __builtin_amdgcn_global_load_lds((const __attribute__((address_space(1))) void*)g,
                                   (__attribute__((address_space(3))) void*)l, 16, 0, 0);
}

__global__ __launch_bounds__(256)
void k_gemm(const uint16_t* __restrict__ A, const uint16_t* __restrict__ B,
            float* __restrict__ C, int M, int N, int K) {
  __shared__ __align__(16) uint16_t As[128 * 32];
  __shared__ __align__(16) uint16_t Bs[128 * 32];

  int bid = blockIdx.x;
  int cpx = gridDim.x >> 3;
  int wg  = (bid & 7) * cpx + (bid >> 3);
  int ntiles = N >> 7;
  int tm = (wg / ntiles) << 7;
  int tn = (wg % ntiles) << 7;

  int tid  = threadIdx.x;
  int lane = tid & 63;
  int wid  = tid >> 6;
  int wm = (wid >> 1) << 6;
  int wn = (wid & 1) << 6;

  f32x4_t acc[4][4] = {};

  int fr = lane & 15;
  int kg = (lane >> 4) << 3;

  int srow = lane >> 2;
  int scol = (lane & 3) << 3;
  const uint16_t* gA = A + (size_t)(tm + (wid << 5) + srow) * K + scol;
  const uint16_t* gB = B + (size_t)(tn + (wid << 5) + srow) * K + scol;
  uint16_t* lA0 = &As[((wid << 5) + 0) * 32];
  uint16_t* lA1 = &As[((wid << 5) + 16) * 32];
  uint16_t* lB0 = &Bs[((wid << 5) + 0) * 32];
  uint16_t* lB1 = &Bs[((wid << 5) + 16) * 32];

  for (int k0 = 0; k0 < K; k0 += 32) {
    gload_lds16(gA, lA0);
    gload_lds16(gA + 16 * (size_t)K, lA1);
    gload_lds16(gB, lB0);
    gload_lds16(gB + 16 * (size_t)K, lB1);
    __syncthreads();

    bf16x8_t af[4], bfr[4];
#pragma unroll
    for (int m = 0; m < 4; ++m)
      af[m] = *(const bf16x8_t*)&As[(wm + (m << 4) + fr) * 32 + kg];
#pragma unroll
    for (int n = 0; n < 4; ++n)
      bfr[n] = *(const bf16x8_t*)&Bs[(wn + (n << 4) + fr) * 32 + kg];

#pragma unroll
    for (int m = 0; m < 4; ++m)
#pragma unroll
      for (int n = 0; n < 4; ++n)
        acc[m][n] = __builtin_amdgcn_mfma_f32_16x16x32_bf16(af[m], bfr[n], acc[m][n], 0, 0, 0);

    __syncthreads();
    gA += 32; gB += 32;
  }

  int crow = tm + wm + ((lane >> 4) << 2);
  int ccol = tn + wn + (lane & 15);
#pragma unroll
  for (int m = 0; m < 4; ++m)
#pragma unroll
    for (int n = 0; n < 4; ++n)
#pragma unroll
      for (int j = 0; j < 4; ++j)
        C[(size_t)(crow + (m << 4) + j) * N + (ccol + (n << 4))] = acc[m][n][j];
}

// ---------------- launch ----------------
extern "C" void kernel_launch(void* const* d_in, const int* in_sizes, int n_in,
                              void* d_out, int out_size, void* d_ws, size_t ws_size,
                              hipStream_t stream) {
  const float* x      = (const float*)d_in[0];
  const float* weight = (const float*)d_in[1];
  const float* lA     = (const float*)d_in[2];
  const float* lB     = (const float*)d_in[3];
  float* out = (float*)d_out;

  const int M = 4 * 2048;   // B*S
  const int N = 4096;       // D_OUT
  const int K = 4096;       // D_IN

  size_t need = (size_t)M * K * 2 + (size_t)N * K * 2;
  if (ws_size < need) return;

  uint16_t* xb = (uint16_t*)d_ws;
  uint16_t* wb = xb + (size_t)M * K;

  // persistent grids: 2048 blocks x 256 = 8 blocks/CU = 32 waves/CU
  k_bitflip_x<<<2048, 256, 0, stream>>>((const float2*)x, (uint32_t*)xb, (M * K) / 2);
  k_make_wb<<<2048, 256, 0, stream>>>((const float2*)weight, lA, lB, (uint32_t*)wb, (N * K) / 2);

  dim3 grid((M / 128) * (N / 128));   // 2048, divisible by 8
  k_gemm<<<grid, 256, 0, stream>>>(xb, wb, out, M, N, K);
}

// Round 3
// 1762.200 us; speedup vs baseline: 1.1445x; 1.0529x over previous
//
#include <hip/hip_runtime.h>
#include <hip/hip_bf16.h>
#include <stdint.h>

#define DEV __device__ __forceinline__

typedef uint32_t u32x4 __attribute__((ext_vector_type(4)));

// ---------------- Threefry-2x32, 4 independent chains interleaved ----------
// JAX partitionable path: counter=(0,n), draw = out0^out1. Exactness verified
// (absmax 8.0 in rounds 1-2). 4-wide rounds give per-wave ILP=4.

DEV uint32_t rotl1(uint32_t x, uint32_t r) {
  return __builtin_amdgcn_alignbit(x, x, 32u - r);
}
DEV u32x4 rotl4(u32x4 x, uint32_t r) {
  u32x4 o;
  o.x = rotl1(x.x, r); o.y = rotl1(x.y, r);
  o.z = rotl1(x.z, r); o.w = rotl1(x.w, r);
  return o;
}

DEV u32x4 tf_bits4(uint32_t k0, uint32_t k1, u32x4 n) {
  uint32_t ks2 = k0 ^ k1 ^ 0x1BD11BDAu;
  u32x4 x1 = n + k1;
  u32x4 x0 = x1 + k0;                    // round-1 add folded
  x1 = rotl4(x1, 13) ^ x0;
#define TF_R4(r) { x0 += x1; x1 = rotl4(x1, r) ^ x0; }
  TF_R4(15) TF_R4(26) TF_R4(6)            x0 += k1;  x1 += ks2 + 1u;
  TF_R4(17) TF_R4(29) TF_R4(16) TF_R4(24) x0 += ks2; x1 += k0 + 2u;
  TF_R4(13) TF_R4(15) TF_R4(26) TF_R4(6)  x0 += k0;  x1 += k1 + 3u;
  TF_R4(17) TF_R4(29) TF_R4(16) TF_R4(24) x0 += k1;  x1 += ks2 + 4u;
  TF_R4(13) TF_R4(15) TF_R4(26) TF_R4(6)  x0 += ks2; x1 += k0 + 5u;
#undef TF_R4
  return x0 ^ x1;
}

// constexpr host-side threefry for fold_in key derivation (compile-time)
struct KP { uint32_t a, b; };
constexpr KP tf_pair_ct(uint32_t k0, uint32_t k1, uint32_t c0, uint32_t c1) {
  uint32_t ks2 = k0 ^ k1 ^ 0x1BD11BDAu;
  uint32_t x0 = c0 + k0, x1 = c1 + k1;
  const uint32_t R[2][4] = {{13u,15u,26u,6u},{17u,29u,16u,24u}};
  uint32_t ks[3] = {k0, k1, ks2};
  for (int g = 0; g < 5; ++g) {
    for (int j = 0; j < 4; ++j) {
      x0 += x1;
      uint32_t r = R[g & 1][j];
      x1 = ((x1 << r) | (x1 >> (32u - r))) ^ x0;
    }
    x0 += ks[(g + 1) % 3];
    x1 += ks[(g + 2) % 3] + (uint32_t)(g + 1);
  }
  return {x0, x1};
}

template <int H> struct KeyArr { uint32_t k0[H]; uint32_t k1[H]; };
template <int H> constexpr KeyArr<H> make_keys(uint32_t seed) {
  KeyArr<H> K{};
  for (int i = 0; i < H; ++i) {
    KP p = tf_pair_ct(0u, seed, 0u, (uint32_t)i);
    K.k0[i] = p.a; K.k1[i] = p.b;
  }
  return K;
}

constexpr KeyArr<10> XE = make_keys<10>(0u);
constexpr KeyArr<6>  XF = make_keys<6>(1u);
constexpr KeyArr<12> WE = make_keys<12>(2u);
constexpr KeyArr<8>  WF = make_keys<8>(3u);

#define EXP_MASK  0x7F800000u
#define FRAC_MASK 0x007FFFFFu

// flip 4 consecutive elements (flat index n0..n0+3); returns flipped fp32 bits
template <int HE, int HF>
DEV u32x4 flip_bits4(u32x4 vbits, const KeyArr<HE>& KE, const KeyArr<HF>& KF,
                     uint32_t n0, float zero_t) {
  u32x4 n = {n0, n0 + 1u, n0 + 2u, n0 + 3u};
  u32x4 me = {EXP_MASK, EXP_MASK, EXP_MASK, EXP_MASK};
#pragma unroll
  for (int h = 0; h < HE; ++h) me &= tf_bits4(KE.k0[h], KE.k1[h], n);
  u32x4 mf = {FRAC_MASK, FRAC_MASK, FRAC_MASK, FRAC_MASK};
#pragma unroll
  for (int h = 0; h < HF; ++h) mf &= tf_bits4(KF.k0[h], KF.k1[h], n);
  u32x4 bits = vbits ^ (me | mf);
  u32x4 out;
#pragma unroll
  for (int e = 0; e < 4; ++e) {
    uint32_t b = bits[e];
    // NaN/inf fail (|y| <= t) anyway -> finite check is redundant
    float ay = __uint_as_float(b & 0x7FFFFFFFu);
    out[e] = (ay <= zero_t) ? b : 0u;
  }
  return out;
}

// round fp32 raw bits to bf16-RNE, pack pair into one u32 (lo=first)
DEV uint32_t pack2_bf16(uint32_t u0, uint32_t u1) {
  u0 += 0x7FFFu + ((u0 >> 16) & 1u);
  u1 += 0x7FFFu + ((u1 >> 16) & 1u);
  return __builtin_amdgcn_perm(u1, u0, 0x07060302u);
}

typedef float f32x4_v __attribute__((ext_vector_type(4)));

// ---------------- Stage 1: bitflip(x) -> bf16 (4 elems/thread/iter) ---------
__global__ __launch_bounds__(256)
void k_bitflip_x(const u32x4* __restrict__ x, uint2* __restrict__ xb, int n_quads) {
  int stride = gridDim.x * blockDim.x;
#pragma unroll 1
  for (int q = blockIdx.x * blockDim.x + threadIdx.x; q < n_quads; q += stride) {
    u32x4 v = x[q];
    u32x4 b = flip_bits4<10, 6>(v, XE, XF, (uint32_t)q * 4u, 1000.0f);
    uint2 o;
    o.x = pack2_bf16(b.x, b.y);
    o.y = pack2_bf16(b.z, b.w);
    xb[q] = o;
  }
}

// ---------------- Stage 2: w = weight + loraB@loraA, bitflip -> bf16 --------
__global__ __launch_bounds__(256)
void k_make_wb(const f32x4_v* __restrict__ weight, const float* __restrict__ lA,
               const float* __restrict__ lB, uint2* __restrict__ wb, int n_quads) {
  int stride = gridDim.x * blockDim.x;
#pragma unroll 1
  for (int q = blockIdx.x * blockDim.x + threadIdx.x; q < n_quads; q += stride) {
    uint32_t n0 = (uint32_t)q * 4u;
    int o = (int)(n0 >> 12);          // D_IN = 4096
    int c = (int)(n0 & 4095u);
    f32x4_v acc = weight[q];
#pragma unroll
    for (int r = 0; r < 32; ++r) {
      f32x4_v a = *(const f32x4_v*)&lA[(r << 12) + c];
      float  b = lB[(o << 5) + r];
      acc.x += b * a.x; acc.y += b * a.y;
      acc.z += b * a.z; acc.w += b * a.w;
    }
    u32x4 vb = {__float_as_uint(acc.x), __float_as_uint(acc.y),
                __float_as_uint(acc.z), __float_as_uint(acc.w)};
    u32x4 bo = flip_bits4<12, 8>(vb, WE, WF, n0, 100.0f);
    uint2 ov;
    ov.x = pack2_bf16(bo.x, bo.y);
    ov.y = pack2_bf16(bo.z, bo.w);
    wb[q] = ov;
  }
}

// ---------------- Stage 3: GEMM  C[m,n] = sum_k A[m,k]*B[n,k]  (m97 structure)
typedef __bf16 bf16x8_t __attribute__((ext_vector_type(8)));
typedef float  f32x4_t  __attribute__((ext_vector_type(4)));

DEV void gload_lds16(const uint16_t* g, uint16_t* l) {
  __builtin_amdgcn_global_load_lds((const __attribute__((address_space(1))) void*)g,
                                   (__attribute__((address_space(3))) void*)l, 16, 0, 0);
}

__global__ __launch_bounds__(256)
void k_gemm(const uint16_t* __restrict__ A, const uint16_t* __restrict__ B,
            float* __restrict__ C, int M, int N, int K) {
  __shared__ __align__(16) uint16_t As[128 * 32];
  __shared__ __align__(16) uint16_t Bs[128 * 32];

  int bid = blockIdx.x;
  int cpx = gridDim.x >> 3;
  int wg  = (bid & 7) * cpx + (bid >> 3);
  int ntiles = N >> 7;
  int tm = (wg / ntiles) << 7;
  int tn = (wg % ntiles) << 7;

  int tid  = threadIdx.x;
  int lane = tid & 63;
  int wid  = tid >> 6;
  int wm = (wid >> 1) << 6;
  int wn = (wid & 1) << 6;

  f32x4_t acc[4][4] = {};

  int fr = lane & 15;
  int kg = (lane >> 4) << 3;

  int srow = lane >> 2;
  int scol = (lane & 3) << 3;
  const uint16_t* gA = A + (size_t)(tm + (wid << 5) + srow) * K + scol;
  const uint16_t* gB = B + (size_t)(tn + (wid << 5) + srow) * K + scol;
  uint16_t* lA0 = &As[((wid << 5) + 0) * 32];
  uint16_t* lA1 = &As[((wid << 5) + 16) * 32];
  uint16_t* lB0 = &Bs[((wid << 5) + 0) * 32];
  uint16_t* lB1 = &Bs[((wid << 5) + 16) * 32];

  for (int k0 = 0; k0 < K; k0 += 32) {
    gload_lds16(gA, lA0);
    gload_lds16(gA + 16 * (size_t)K, lA1);
    gload_lds16(gB, lB0);
    gload_lds16(gB + 16 * (size_t)K, lB1);
    __syncthreads();

    bf16x8_t af[4], bfr[4];
#pragma unroll
    for (int m = 0; m < 4; ++m)
      af[m] = *(const bf16x8_t*)&As[(wm + (m << 4) + fr) * 32 + kg];
#pragma unroll
    for (int n = 0; n < 4; ++n)
      bfr[n] = *(const bf16x8_t*)&Bs[(wn + (n << 4) + fr) * 32 + kg];

#pragma unroll
    for (int m = 0; m < 4; ++m)
#pragma unroll
      for (int n = 0; n < 4; ++n)
        acc[m][n] = __builtin_amdgcn_mfma_f32_16x16x32_bf16(af[m], bfr[n], acc[m][n], 0, 0, 0);

    __syncthreads();
    gA += 32; gB += 32;
  }

  int crow = tm + wm + ((lane >> 4) << 2);
  int ccol = tn + wn + (lane & 15);
#pragma unroll
  for (int m = 0; m < 4; ++m)
#pragma unroll
    for (int n = 0; n < 4; ++n)
#pragma unroll
      for (int j = 0; j < 4; ++j)
        C[(size_t)(crow + (m << 4) + j) * N + (ccol + (n << 4))] = acc[m][n][j];
}

// ---------------- launch ----------------
extern "C" void kernel_launch(void* const* d_in, const int* in_sizes, int n_in,
                              void* d_out, int out_size, void* d_ws, size_t ws_size,
                              hipStream_t stream) {
  const float* x      = (const float*)d_in[0];
  const float* weight = (const float*)d_in[1];
  const float* lA     = (const float*)d_in[2];
  const float* lB     = (const float*)d_in[3];
  float* out = (float*)d_out;

  const int M = 4 * 2048;   // B*S
  const int N = 4096;       // D_OUT
  const int K = 4096;       // D_IN

  size_t need = (size_t)M * K * 2 + (size_t)N * K * 2;
  if (ws_size < need) return;

  uint16_t* xb = (uint16_t*)d_ws;
  uint16_t* wb = xb + (size_t)M * K;

  k_bitflip_x<<<2048, 256, 0, stream>>>((const u32x4*)x, (uint2*)xb, (M * K) / 4);
  k_make_wb<<<2048, 256, 0, stream>>>((const f32x4_v*)weight, lA, lB, (uint2*)wb, (N * K) / 4);

  dim3 grid((M / 128) * (N / 128));   // 2048, divisible by 8
  k_gemm<<<grid, 256, 0, stream>>>(xb, wb, out, M, N, K);
}